// Round 10
// baseline (83.627 us; speedup 1.0000x reference)
//
#include <hip/hip_runtime.h>
#include <math.h>

#define D    128
#define NT   256             // B*T
#define HD   32
#define LD   32
#define PADW 132             // padded row (floats)

// ---------------------------------------------------------------------------
// K12: one block per token n (grid 256 x 1024 thr).
//  P1: thread (h, i-quad): pa'[h][i] = b1[h]+z[i]·W1a[h], pb[h][i] -> LDS.
//  P2: rank-1 relu-split terms lin[kind][i] (relu(x) = x/2 + |x|/2).
//  P3: 4i x 4j per thread: acc += (w2[h]/2)*|pa'+pb| over 32 h.
//  epi: atomicAdd f32 token-S into G (64 KB, L2-resident). No D round-trip,
//       no bf16 quantization, no transpose epilogue.
// ---------------------------------------------------------------------------
__global__ __launch_bounds__(1024) void fused_scores_atomic(
    const float* __restrict__ z, const float* __restrict__ W1,
    const float* __restrict__ b1, const float* __restrict__ W2,
    float* __restrict__ G)
{
    __shared__ float zt[LD][PADW];      // 16.9 KB (dead after P1)
    __shared__ float spa[HD][PADW];     // 16.9 KB
    __shared__ float spb[HD][PADW];     // 16.9 KB
    __shared__ float lin[2][D];         // 1 KB

    const int t = threadIdx.x;
    const int n = blockIdx.x;

    // ---- stage z transposed: 1024 float4, 1/thread ----
    {
        const float4* zsrc = (const float4*)(z + (size_t)n * (D * LD));
        float4 v = zsrc[t];
        int i = t >> 3;                  // 0..127
        int l = (t & 7) * 4;             // 0..28
        zt[l + 0][i] = v.x; zt[l + 1][i] = v.y;
        zt[l + 2][i] = v.z; zt[l + 3][i] = v.w;
    }

    // ---- W1 row h into VGPRs ----
    const int h  = t & 31;
    const int iq = t >> 5;               // 0..31
    float wa[LD], wb[LD];
    #pragma unroll
    for (int k = 0; k < 8; ++k) {
        *(float4*)&wa[k*4] = *(const float4*)&W1[h * 64 + k*4];
        *(float4*)&wb[k*4] = *(const float4*)&W1[h * 64 + 32 + k*4];
    }
    const float bias = b1[h];
    __syncthreads();

    // ---- P1: 4 i's x 1 h per thread, 8 independent fma chains ----
    {
        float a[4], c[4];
        #pragma unroll
        for (int r = 0; r < 4; ++r) { a[r] = bias; c[r] = 0.f; }
        #pragma unroll
        for (int l = 0; l < LD; ++l) {
            float4 zv = *(const float4*)&zt[l][iq * 4];
            float zr[4] = {zv.x, zv.y, zv.z, zv.w};
            #pragma unroll
            for (int r = 0; r < 4; ++r) {
                a[r] = fmaf(zr[r], wa[l], a[r]);
                c[r] = fmaf(zr[r], wb[l], c[r]);
            }
        }
        *(float4*)&spa[h][iq * 4] = make_float4(a[0], a[1], a[2], a[3]);
        *(float4*)&spb[h][iq * 4] = make_float4(c[0], c[1], c[2], c[3]);
    }
    __syncthreads();

    float w2r[HD];                       // uniform -> scalarized
    #pragma unroll
    for (int q = 0; q < HD; ++q) w2r[q] = 0.5f * W2[q];

    // ---- P2: rank-1 linear terms, 256 threads ----
    if (t < 256) {
        const int kind = t >> 7, i2 = t & 127;
        float s = 0.f;
        #pragma unroll
        for (int hq = 0; hq < HD; ++hq) {
            float v = kind ? spb[hq][i2] : spa[hq][i2];
            s = fmaf(w2r[hq], v, s);
        }
        lin[kind][i2] = s;
    }
    __syncthreads();

    // ---- P3: abs part, 4i x 4j per thread ----
    const int tx = t & 31;               // j-quad
    const int ty = t >> 5;               // i-quad
    float acc[4][4];
    #pragma unroll
    for (int r = 0; r < 4; ++r)
        #pragma unroll
        for (int c = 0; c < 4; ++c) acc[r][c] = 0.f;

    #pragma unroll 4
    for (int hh = 0; hh < HD; ++hh) {
        float4 av = *(const float4*)&spa[hh][ty * 4];
        float4 bv = *(const float4*)&spb[hh][tx * 4];
        const float w = w2r[hh];
        float ar[4] = {av.x, av.y, av.z, av.w};
        float br[4] = {bv.x, bv.y, bv.z, bv.w};
        #pragma unroll
        for (int r = 0; r < 4; ++r)
            #pragma unroll
            for (int c = 0; c < 4; ++c)
                acc[r][c] = fmaf(w, fabsf(ar[r] + br[c]), acc[r][c]);
    }

    // ---- add linear terms; atomic-accumulate token S into G ----
    {
        float cai[4], cbj[4];
        #pragma unroll
        for (int r = 0; r < 4; ++r) cai[r] = lin[0][ty * 4 + r];
        #pragma unroll
        for (int c = 0; c < 4; ++c) cbj[c] = lin[1][tx * 4 + c];

        const int ro = n & 3, co = (n >> 2) & 3;   // per-block stagger
        #pragma unroll
        for (int r = 0; r < 4; ++r) {
            #pragma unroll
            for (int c = 0; c < 4; ++c) {
                const int rr = (r + ro) & 3;
                const int cc = (c + co) & 3;
                float v = acc[rr][cc] + cai[rr] + cbj[cc];
                __hip_atomic_fetch_add(&G[(ty * 4 + rr) * D + tx * 4 + cc],
                                       v, __ATOMIC_RELAXED,
                                       __HIP_MEMORY_SCOPE_AGENT);
            }
        }
    }
}

// ---------------------------------------------------------------------------
// Finalize: A from antisym mean of G (64 KB, L2-hot), sigmoids, Wm.
// b2 cancels exactly in G[i][j] - G[j][i]. grid 64 x 256.
// ---------------------------------------------------------------------------
__global__ __launch_bounds__(256) void finalize_kernel(
    const float* __restrict__ G, const float* __restrict__ Wmag,
    float* __restrict__ out)
{
    const int idx = blockIdx.x * 256 + threadIdx.x;   // 0..16383
    const int i = idx >> 7, j = idx & 127;

    float gij = G[idx];
    float gji = G[j * D + i];
    float av  = (gij - gji) * (1.0f / 256.0f);        // mean over n; TAU = 1
    float dir = 1.0f / (1.0f + __expf(-av));
    float wm  = 0.5f * (Wmag[i * D + j] + Wmag[j * D + i]);
    float A;
    if (i == j) { wm = 0.f; A = 0.f; }
    else        { A = dir / (1.0f + __expf(-wm)); }
    out[idx]         = A;
    out[D * D + idx] = wm;
}

extern "C" void kernel_launch(void* const* d_in, const int* in_sizes, int n_in,
                              void* d_out, int out_size, void* d_ws, size_t ws_size,
                              hipStream_t stream)
{
    const float* z    = (const float*)d_in[0];   // (4,64,128,32)
    const float* Wmag = (const float*)d_in[1];   // (128,128)
    const float* W1   = (const float*)d_in[2];   // (32,64)
    const float* b1   = (const float*)d_in[3];   // (32,)
    const float* W2   = (const float*)d_in[4];   // (1,32)
    // d_in[5] = b2: cancels in scores - scores^T.

    float* G   = (float*)d_ws;                   // 16384 f32 = 64 KB
    float* out = (float*)d_out;

    // zero the accumulator every call (in-graph, replay-safe)
    hipMemsetAsync(G, 0, D * D * sizeof(float), stream);
    fused_scores_atomic<<<NT, 1024, 0, stream>>>(z, W1, b1, W2, G);
    finalize_kernel<<<(D * D) / 256, 256, 0, stream>>>(G, Wmag, out);
}

// Round 11
// 40.418 us; speedup vs baseline: 2.0691x; 2.0691x over previous
//
#include <hip/hip_runtime.h>
#include <hip/hip_bf16.h>
#include <math.h>

#define D    128
#define NT   256             // B*T
#define HD   32
#define LD   32
#define PADW 132             // padded row length (f32 / u16 elems)

static __device__ inline unsigned short f2bf(float f) {
    __hip_bfloat16 b = __float2bfloat16(f);
    return *reinterpret_cast<unsigned short*>(&b);
}
static __device__ inline float bf2f(unsigned int u16v) {
    union { unsigned int i; float f; } v;
    v.i = u16v << 16;
    return v.f;
}

union SmemA {                        // z (P1) overlaid with lin (P2+)
    float zt[LD][PADW];              // z transposed zt[l][i], 16.9 KB
    float lin[2][D];                 // rank-1 relu-split terms, 1 KB
};
union SmemB {                        // pa/pb overlaid with S-transpose buf
    struct { float spa[HD][PADW]; float spb[HD][PADW]; } p;   // 33.8 KB
    unsigned short st[D][PADW];                               // 33.8 KB
};

// ---------------------------------------------------------------------------
// K12: one block per token n (grid 256 x 1024 thr). Same P1/P2/P3 as R9.
//  epi: S -> bf16 LDS transpose -> write ONLY upper triangle of
//       D = S - S^T (4 MB bf16 total; lower half derivable by negation).
// ---------------------------------------------------------------------------
__global__ __launch_bounds__(1024, 4) void fused_pab_scores(
    const float* __restrict__ z, const float* __restrict__ W1,
    const float* __restrict__ b1, const float* __restrict__ W2,
    unsigned short* __restrict__ Dp)
{
    __shared__ SmemA sa;
    __shared__ SmemB sb;

    const int t = threadIdx.x;
    const int n = blockIdx.x;

    // ---- stage z transposed: 1024 float4, 1/thread ----
    {
        const float4* zsrc = (const float4*)(z + (size_t)n * (D * LD));
        float4 v = zsrc[t];
        int i = t >> 3;                  // 0..127
        int l = (t & 7) * 4;             // 0..28
        sa.zt[l + 0][i] = v.x; sa.zt[l + 1][i] = v.y;
        sa.zt[l + 2][i] = v.z; sa.zt[l + 3][i] = v.w;
    }

    // ---- W1 row h into VGPRs ----
    const int h  = t & 31;
    const int iq = t >> 5;               // 0..31
    float wa[LD], wb[LD];
    #pragma unroll
    for (int k = 0; k < 8; ++k) {
        *(float4*)&wa[k*4] = *(const float4*)&W1[h * 64 + k*4];
        *(float4*)&wb[k*4] = *(const float4*)&W1[h * 64 + 32 + k*4];
    }
    const float bias = b1[h];
    __syncthreads();

    // ---- P1: 4 i's x 1 h per thread, 8 independent fma chains ----
    {
        float a[4], c[4];
        #pragma unroll
        for (int r = 0; r < 4; ++r) { a[r] = bias; c[r] = 0.f; }
        #pragma unroll
        for (int l = 0; l < LD; ++l) {
            float4 zv = *(const float4*)&sa.zt[l][iq * 4];
            float zr[4] = {zv.x, zv.y, zv.z, zv.w};
            #pragma unroll
            for (int r = 0; r < 4; ++r) {
                a[r] = fmaf(zr[r], wa[l], a[r]);
                c[r] = fmaf(zr[r], wb[l], c[r]);
            }
        }
        *(float4*)&sb.p.spa[h][iq * 4] = make_float4(a[0], a[1], a[2], a[3]);
        *(float4*)&sb.p.spb[h][iq * 4] = make_float4(c[0], c[1], c[2], c[3]);
    }
    __syncthreads();                     // zt dead after here

    float w2r[HD];                       // uniform -> scalarized
    #pragma unroll
    for (int q = 0; q < HD; ++q) w2r[q] = 0.5f * W2[q];

    // ---- P2: rank-1 linear terms (relu(x) = x/2 + |x|/2), 256 threads ----
    if (t < 256) {
        const int kind = t >> 7, i2 = t & 127;
        float s = 0.f;
        #pragma unroll
        for (int hq = 0; hq < HD; ++hq) {
            float v = kind ? sb.p.spb[hq][i2] : sb.p.spa[hq][i2];
            s = fmaf(w2r[hq], v, s);
        }
        sa.lin[kind][i2] = s;
    }
    __syncthreads();

    // ---- P3: abs part, 4i x 4j per thread ----
    const int tx = t & 31;               // j-quad
    const int ty = t >> 5;               // i-quad
    float acc[4][4];
    #pragma unroll
    for (int r = 0; r < 4; ++r)
        #pragma unroll
        for (int c = 0; c < 4; ++c) acc[r][c] = 0.f;

    #pragma unroll 4
    for (int hh = 0; hh < HD; ++hh) {
        float4 av = *(const float4*)&sb.p.spa[hh][ty * 4];
        float4 bv = *(const float4*)&sb.p.spb[hh][tx * 4];
        const float w = w2r[hh];
        float ar[4] = {av.x, av.y, av.z, av.w};
        float br[4] = {bv.x, bv.y, bv.z, bv.w};
        #pragma unroll
        for (int r = 0; r < 4; ++r)
            #pragma unroll
            for (int c = 0; c < 4; ++c)
                acc[r][c] = fmaf(w, fabsf(ar[r] + br[c]), acc[r][c]);
    }

    // ---- add linear terms ----
    {
        float cai[4], cbj[4];
        #pragma unroll
        for (int r = 0; r < 4; ++r) cai[r] = sa.lin[0][ty * 4 + r];
        #pragma unroll
        for (int c = 0; c < 4; ++c) cbj[c] = sa.lin[1][tx * 4 + c];
        #pragma unroll
        for (int r = 0; r < 4; ++r)
            #pragma unroll
            for (int c = 0; c < 4; ++c)
                acc[r][c] += cai[r] + cbj[c];
    }
    __syncthreads();                     // spa/spb dead -> st overlay

    // ---- epilogue: S -> bf16 LDS transpose; write UPPER TRIANGLE of D ----
    #pragma unroll
    for (int r = 0; r < 4; ++r) {
        unsigned int p0 = ((unsigned int)f2bf(acc[r][1]) << 16) | f2bf(acc[r][0]);
        unsigned int p1 = ((unsigned int)f2bf(acc[r][3]) << 16) | f2bf(acc[r][2]);
        *(uint2*)&sb.st[ty * 4 + r][tx * 4] = make_uint2(p0, p1);
    }
    __syncthreads();

    unsigned short* Dn = Dp + (size_t)n * (D * D);
    if (tx > ty) {                       // fully above diagonal: 4x4 packed
        float dre[4][4];
        #pragma unroll
        for (int c = 0; c < 4; ++c) {
            int j = tx * 4 + c;
            uint2 tv = *(const uint2*)&sb.st[j][ty * 4];    // S[j][ty*4..+3]
            dre[0][c] = acc[0][c] - bf2f(tv.x & 0xffff);
            dre[1][c] = acc[1][c] - bf2f(tv.x >> 16);
            dre[2][c] = acc[2][c] - bf2f(tv.y & 0xffff);
            dre[3][c] = acc[3][c] - bf2f(tv.y >> 16);
        }
        #pragma unroll
        for (int r = 0; r < 4; ++r) {
            unsigned int p0 = ((unsigned int)f2bf(dre[r][1]) << 16) | f2bf(dre[r][0]);
            unsigned int p1 = ((unsigned int)f2bf(dre[r][3]) << 16) | f2bf(dre[r][2]);
            *(uint2*)&Dn[(ty * 4 + r) * D + tx * 4] = make_uint2(p0, p1);
        }
    } else if (tx == ty) {               // diagonal tile: cells j > i only
        #pragma unroll
        for (int r = 0; r < 4; ++r) {
            #pragma unroll
            for (int c = 0; c < 4; ++c) {
                if (c > r) {
                    int i = ty * 4 + r, j = tx * 4 + c;
                    float sji = bf2f((unsigned int)sb.st[j][i]);
                    Dn[i * D + j] = f2bf(acc[r][c] - sji);
                }
            }
        }
    }
}

// ---------------------------------------------------------------------------
// K3: row-per-block triangle reduce. Block i sums D[n][i][j] over n for
// j > i (coalesced in j), emits A[i][j] (sigma(+av)) AND A[j][i]
// (sigma(-av)) plus symmetric Wm — no transposed global reads.
// ---------------------------------------------------------------------------
__global__ __launch_bounds__(256) void finalize_tri(
    const unsigned short* __restrict__ Dp, const float* __restrict__ Wmag,
    float* __restrict__ out)
{
    const int i = blockIdx.x;            // 0..127
    const int j = i + 1 + threadIdx.x;

    if (threadIdx.x == 0) {              // diagonal
        out[i * D + i]         = 0.f;
        out[D * D + i * D + i] = 0.f;
    }
    if (j > 127) return;

    float s = 0.f;
    #pragma unroll 8
    for (int n = 0; n < NT; ++n)
        s += bf2f((unsigned int)Dp[(size_t)n * (D * D) + i * D + j]);

    const float av   = s * (1.0f / 256.0f);      // mean over n; TAU = 1
    const float wm   = 0.5f * (Wmag[i * D + j] + Wmag[j * D + i]);
    const float smw  = 1.0f / (1.0f + __expf(-wm));
    const float dirp = 1.0f / (1.0f + __expf(-av));
    out[i * D + j]         = dirp * smw;          // A[i][j]
    out[j * D + i]         = (1.0f - dirp) * smw; // A[j][i]: sigma(-av)
    out[D * D + i * D + j] = wm;
    out[D * D + j * D + i] = wm;
}

extern "C" void kernel_launch(void* const* d_in, const int* in_sizes, int n_in,
                              void* d_out, int out_size, void* d_ws, size_t ws_size,
                              hipStream_t stream)
{
    const float* z    = (const float*)d_in[0];   // (4,64,128,32)
    const float* Wmag = (const float*)d_in[1];   // (128,128)
    const float* W1   = (const float*)d_in[2];   // (32,64)
    const float* b1   = (const float*)d_in[3];   // (32,)
    const float* W2   = (const float*)d_in[4];   // (1,32)
    // d_in[5] = b2: cancels in scores - scores^T.

    unsigned short* Dp = (unsigned short*)d_ws;  // bf16 D upper-tri, [NT][D][D]
    float* out = (float*)d_out;

    fused_pab_scores<<<NT, 1024, 0, stream>>>(z, W1, b1, W2, Dp);
    finalize_tri<<<D, 256, 0, stream>>>(Dp, Wmag, out);
}

// Round 12
// 33.111 us; speedup vs baseline: 2.5257x; 1.2207x over previous
//
#include <hip/hip_runtime.h>
#include <hip/hip_bf16.h>
#include <math.h>

#define D    128
#define NT   256             // B*T
#define HD   32
#define LD   32
#define PADW 132             // padded row length (f32 / u16 elems)

static __device__ inline unsigned short f2bf(float f) {
    __hip_bfloat16 b = __float2bfloat16(f);
    return *reinterpret_cast<unsigned short*>(&b);
}
static __device__ inline float bf2f(unsigned int u16v) {
    union { unsigned int i; float f; } v;
    v.i = u16v << 16;
    return v.f;
}

union SmemA {                        // z (P1) overlaid with lin (P2+)
    float zt[LD][PADW];              // z transposed zt[l][i], 16.9 KB
    float lin[2][D];                 // rank-1 relu-split terms, 1 KB
};
union SmemB {                        // pa/pb overlaid with S-transpose buf
    struct { float spa[HD][PADW]; float spb[HD][PADW]; } p;   // 33.8 KB
    unsigned short st[D][PADW];                               // 33.8 KB
};

// ---------------------------------------------------------------------------
// K12: one block per token n, 1024 threads. NO occupancy cap: grid=256 means
// 1 block/CU regardless, so let the allocator use ~128+ VGPRs (R9's
// __launch_bounds__(1024,4) forced 64 VGPR -> W1 could not stay resident).
// ---------------------------------------------------------------------------
__global__ __launch_bounds__(1024) void fused_pab_scores(
    const float* __restrict__ z, const float* __restrict__ W1,
    const float* __restrict__ b1, const float* __restrict__ W2,
    unsigned short* __restrict__ Dp)
{
    __shared__ SmemA sa;
    __shared__ SmemB sb;

    const int t = threadIdx.x;
    const int n = blockIdx.x;

    // ---- stage z transposed: 1024 float4, 1/thread ----
    {
        const float4* zsrc = (const float4*)(z + (size_t)n * (D * LD));
        float4 v = zsrc[t];
        int i = t >> 3;                  // 0..127
        int l = (t & 7) * 4;             // 0..28
        sa.zt[l + 0][i] = v.x; sa.zt[l + 1][i] = v.y;
        sa.zt[l + 2][i] = v.z; sa.zt[l + 3][i] = v.w;
    }

    // ---- W1 row h into VGPRs ----
    const int h  = t & 31;
    const int iq = t >> 5;               // 0..31
    float wa[LD], wb[LD];
    #pragma unroll
    for (int k = 0; k < 8; ++k) {
        *(float4*)&wa[k*4] = *(const float4*)&W1[h * 64 + k*4];
        *(float4*)&wb[k*4] = *(const float4*)&W1[h * 64 + 32 + k*4];
    }
    const float bias = b1[h];
    __syncthreads();

    // ---- P1: 4 i's x 1 h per thread, 8 independent fma chains ----
    {
        float a[4], c[4];
        #pragma unroll
        for (int r = 0; r < 4; ++r) { a[r] = bias; c[r] = 0.f; }
        #pragma unroll
        for (int l = 0; l < LD; ++l) {
            float4 zv = *(const float4*)&sa.zt[l][iq * 4];
            float zr[4] = {zv.x, zv.y, zv.z, zv.w};
            #pragma unroll
            for (int r = 0; r < 4; ++r) {
                a[r] = fmaf(zr[r], wa[l], a[r]);
                c[r] = fmaf(zr[r], wb[l], c[r]);
            }
        }
        *(float4*)&sb.p.spa[h][iq * 4] = make_float4(a[0], a[1], a[2], a[3]);
        *(float4*)&sb.p.spb[h][iq * 4] = make_float4(c[0], c[1], c[2], c[3]);
    }
    __syncthreads();                     // zt dead after here

    float w2r[HD];                       // uniform -> scalarized
    #pragma unroll
    for (int q = 0; q < HD; ++q) w2r[q] = 0.5f * W2[q];

    // ---- P2: rank-1 linear terms (relu(x) = x/2 + |x|/2), 256 threads ----
    if (t < 256) {
        const int kind = t >> 7, i2 = t & 127;
        float s = 0.f;
        #pragma unroll
        for (int hq = 0; hq < HD; ++hq) {
            float v = kind ? sb.p.spb[hq][i2] : sb.p.spa[hq][i2];
            s = fmaf(w2r[hq], v, s);
        }
        sa.lin[kind][i2] = s;
    }
    __syncthreads();

    // ---- P3: abs part, 4i x 4j per thread ----
    const int tx = t & 31;               // j-quad
    const int ty = t >> 5;               // i-quad
    float acc[4][4];
    #pragma unroll
    for (int r = 0; r < 4; ++r)
        #pragma unroll
        for (int c = 0; c < 4; ++c) acc[r][c] = 0.f;

    #pragma unroll 4
    for (int hh = 0; hh < HD; ++hh) {
        float4 av = *(const float4*)&sb.p.spa[hh][ty * 4];
        float4 bv = *(const float4*)&sb.p.spb[hh][tx * 4];
        const float w = w2r[hh];
        float ar[4] = {av.x, av.y, av.z, av.w};
        float br[4] = {bv.x, bv.y, bv.z, bv.w};
        #pragma unroll
        for (int r = 0; r < 4; ++r)
            #pragma unroll
            for (int c = 0; c < 4; ++c)
                acc[r][c] = fmaf(w, fabsf(ar[r] + br[c]), acc[r][c]);
    }

    // ---- add linear terms ----
    {
        float cai[4], cbj[4];
        #pragma unroll
        for (int r = 0; r < 4; ++r) cai[r] = sa.lin[0][ty * 4 + r];
        #pragma unroll
        for (int c = 0; c < 4; ++c) cbj[c] = sa.lin[1][tx * 4 + c];
        #pragma unroll
        for (int r = 0; r < 4; ++r)
            #pragma unroll
            for (int c = 0; c < 4; ++c)
                acc[r][c] += cai[r] + cbj[c];
    }
    __syncthreads();                     // spa/spb dead -> st overlay

    // ---- epilogue: S -> bf16 LDS, in-block transpose, write D only ----
    #pragma unroll
    for (int r = 0; r < 4; ++r) {
        unsigned int p0 = ((unsigned int)f2bf(acc[r][1]) << 16) | f2bf(acc[r][0]);
        unsigned int p1 = ((unsigned int)f2bf(acc[r][3]) << 16) | f2bf(acc[r][2]);
        *(uint2*)&sb.st[ty * 4 + r][tx * 4] = make_uint2(p0, p1);
    }
    __syncthreads();

    unsigned short* Dn = Dp + (size_t)n * (D * D);
    float dre[4][4];
    #pragma unroll
    for (int c = 0; c < 4; ++c) {
        int j = tx * 4 + c;
        uint2 tv = *(const uint2*)&sb.st[j][ty * 4];    // S[j][ty*4..+3]
        dre[0][c] = acc[0][c] - bf2f(tv.x & 0xffff);
        dre[1][c] = acc[1][c] - bf2f(tv.x >> 16);
        dre[2][c] = acc[2][c] - bf2f(tv.y & 0xffff);
        dre[3][c] = acc[3][c] - bf2f(tv.y >> 16);
    }
    #pragma unroll
    for (int r = 0; r < 4; ++r) {
        unsigned int p0 = ((unsigned int)f2bf(dre[r][1]) << 16) | f2bf(dre[r][0]);
        unsigned int p1 = ((unsigned int)f2bf(dre[r][3]) << 16) | f2bf(dre[r][2]);
        *(uint2*)&Dn[(ty * 4 + r) * D + tx * 4] = make_uint2(p0, p1);
    }
}

// ---------------------------------------------------------------------------
// K3: mean over n of D (8 MB, coalesced uint2), sigmoid/Wm finalize.
// grid 256: block = (row, j-half). thread (g = 16 n-groups, jq = 16 j-quads).
// ---------------------------------------------------------------------------
__global__ __launch_bounds__(256) void finalize_kernel(
    const unsigned short* __restrict__ Dp, const float* __restrict__ Wmag,
    float* __restrict__ out)
{
    __shared__ float red[16][68];

    const int t    = threadIdx.x;
    const int row  = blockIdx.x >> 1;
    const int half = blockIdx.x & 1;
    const int g    = t >> 4;             // n-group 0..15 (16 n's each)
    const int jq   = t & 15;             // j-quad within half
    const int jloc = jq * 4;

    float a4[4] = {0.f, 0.f, 0.f, 0.f};
    #pragma unroll 4
    for (int q = 0; q < 16; ++q) {
        int nn = g * 16 + q;
        uint2 u = *(const uint2*)&Dp[(size_t)nn * (D * D) + row * D + half * 64 + jloc];
        a4[0] += bf2f(u.x & 0xffff); a4[1] += bf2f(u.x >> 16);
        a4[2] += bf2f(u.y & 0xffff); a4[3] += bf2f(u.y >> 16);
    }
    *(float4*)&red[g][jloc] = make_float4(a4[0], a4[1], a4[2], a4[3]);
    __syncthreads();

    if (t < 64) {
        const int j = half * 64 + t;
        float s = 0.f;
        #pragma unroll
        for (int gg = 0; gg < 16; ++gg) s += red[gg][t];

        const int idx = row * D + j;
        float av  = s * (1.0f / 256.0f);     // mean over n; TAU = 1
        float dir = 1.0f / (1.0f + __expf(-av));
        float wm  = 0.5f * (Wmag[row * D + j] + Wmag[j * D + row]);
        float A;
        if (row == j) { wm = 0.f; A = 0.f; }
        else          { A = dir / (1.0f + __expf(-wm)); }
        out[idx]         = A;
        out[D * D + idx] = wm;
    }
}

extern "C" void kernel_launch(void* const* d_in, const int* in_sizes, int n_in,
                              void* d_out, int out_size, void* d_ws, size_t ws_size,
                              hipStream_t stream)
{
    const float* z    = (const float*)d_in[0];   // (4,64,128,32)
    const float* Wmag = (const float*)d_in[1];   // (128,128)
    const float* W1   = (const float*)d_in[2];   // (32,64)
    const float* b1   = (const float*)d_in[3];   // (32,)
    const float* W2   = (const float*)d_in[4];   // (1,32)
    // d_in[5] = b2: cancels in scores - scores^T.

    unsigned short* Dp = (unsigned short*)d_ws;  // bf16 D[n][i][j], 8 MB
    float* out = (float*)d_out;

    fused_pab_scores<<<NT, 1024, 0, stream>>>(z, W1, b1, W2, Dp);
    finalize_kernel<<<NT, 256, 0, stream>>>(Dp, Wmag, out);
}

// Round 13
// 30.118 us; speedup vs baseline: 2.7766x; 1.0994x over previous
//
#include <hip/hip_runtime.h>
#include <hip/hip_bf16.h>
#include <math.h>

#define D    128
#define NT   256             // B*T
#define HD   32
#define LD   32
#define PADW 132             // padded row length (f32 / u16 elems)

static __device__ inline unsigned short f2bf(float f) {
    __hip_bfloat16 b = __float2bfloat16(f);
    return *reinterpret_cast<unsigned short*>(&b);
}
static __device__ inline float bf2f(unsigned int u16v) {
    union { unsigned int i; float f; } v;
    v.i = u16v << 16;
    return v.f;
}

union SmemA {                        // z (P1) overlaid with lin (P2+)
    float zt[LD][PADW];              // z transposed zt[l][i], 16.9 KB
    float lin[2][D];                 // rank-1 relu-split terms, 1 KB
};
union SmemB {                        // pa/pb overlaid with S-transpose buf
    struct { float spa[HD][PADW]; float spb[HD][PADW]; } p;   // 33.8 KB
    unsigned short st[D][PADW];                               // 33.8 KB
};

// ---------------------------------------------------------------------------
// K12: one block per token n, 512 threads. vs R12: P3 tile 8i x 4j
// (3 b128/hh vs 4 per 32 cells: per-CU P3 LDS instrs -25%), 4 barriers
// instead of 5, P2 overlapped with the P3 loop (skew-join, t<256 only).
// ---------------------------------------------------------------------------
__global__ __launch_bounds__(512) void fused_pab_scores(
    const float* __restrict__ z, const float* __restrict__ W1,
    const float* __restrict__ b1, const float* __restrict__ W2,
    unsigned short* __restrict__ Dp)
{
    __shared__ SmemA sa;
    __shared__ SmemB sb;

    const int t = threadIdx.x;
    const int n = blockIdx.x;

    // ---- stage z transposed: 1024 float4, 2/thread ----
    {
        const float4* zsrc = (const float4*)(z + (size_t)n * (D * LD));
        #pragma unroll
        for (int q = 0; q < 2; ++q) {
            int f = t + q * 512;
            float4 v = zsrc[f];
            int i = f >> 3;              // 0..127
            int l = (f & 7) * 4;         // 0..28
            sa.zt[l + 0][i] = v.x; sa.zt[l + 1][i] = v.y;
            sa.zt[l + 2][i] = v.z; sa.zt[l + 3][i] = v.w;
        }
    }

    // ---- W1 row h into VGPRs ----
    const int h  = t & 31;
    const int iq = t >> 5;               // 0..15 (i-oct for P1)
    float wa[LD], wb[LD];
    #pragma unroll
    for (int k = 0; k < 8; ++k) {
        *(float4*)&wa[k*4] = *(const float4*)&W1[h * 64 + k*4];
        *(float4*)&wb[k*4] = *(const float4*)&W1[h * 64 + 32 + k*4];
    }
    const float bias = b1[h];
    __syncthreads();                     // (1) z staged

    // ---- P1: 8 i's x 1 h per thread, 16 independent fma chains ----
    {
        float a[8], c[8];
        #pragma unroll
        for (int r = 0; r < 8; ++r) { a[r] = bias; c[r] = 0.f; }
        #pragma unroll
        for (int l = 0; l < LD; ++l) {
            float4 z0 = *(const float4*)&sa.zt[l][iq * 8];
            float4 z1 = *(const float4*)&sa.zt[l][iq * 8 + 4];
            float zr[8] = {z0.x, z0.y, z0.z, z0.w, z1.x, z1.y, z1.z, z1.w};
            #pragma unroll
            for (int r = 0; r < 8; ++r) {
                a[r] = fmaf(zr[r], wa[l], a[r]);
                c[r] = fmaf(zr[r], wb[l], c[r]);
            }
        }
        *(float4*)&sb.p.spa[h][iq * 8]     = make_float4(a[0], a[1], a[2], a[3]);
        *(float4*)&sb.p.spa[h][iq * 8 + 4] = make_float4(a[4], a[5], a[6], a[7]);
        *(float4*)&sb.p.spb[h][iq * 8]     = make_float4(c[0], c[1], c[2], c[3]);
        *(float4*)&sb.p.spb[h][iq * 8 + 4] = make_float4(c[4], c[5], c[6], c[7]);
    }

    float w2r[HD];                       // uniform -> scalarized
    #pragma unroll
    for (int q = 0; q < HD; ++q) w2r[q] = 0.5f * W2[q];
    __syncthreads();                     // (2) spa/spb ready; zt dead

    // ---- P2 (t<256 only, overlaps P3 loop; no barrier before P3) ----
    if (t < 256) {
        const int kind = t >> 7, i2 = t & 127;
        float s = 0.f;
        #pragma unroll
        for (int hq = 0; hq < HD; ++hq) {
            float v = kind ? sb.p.spb[hq][i2] : sb.p.spa[hq][i2];
            s = fmaf(w2r[hq], v, s);
        }
        sa.lin[kind][i2] = s;            // consumed after barrier (3)
    }

    // ---- P3: abs part, 8i x 4j per thread ----
    const int tx = t & 31;               // j-quad (j = tx*4)
    const int ty = t >> 5;               // i-oct  (i = ty*8)
    float acc[8][4];
    #pragma unroll
    for (int r = 0; r < 8; ++r)
        #pragma unroll
        for (int c = 0; c < 4; ++c) acc[r][c] = 0.f;

    #pragma unroll 4
    for (int hh = 0; hh < HD; ++hh) {
        float4 a0 = *(const float4*)&sb.p.spa[hh][ty * 8];
        float4 a1 = *(const float4*)&sb.p.spa[hh][ty * 8 + 4];
        float4 bv = *(const float4*)&sb.p.spb[hh][tx * 4];
        const float w = w2r[hh];
        float ar[8] = {a0.x, a0.y, a0.z, a0.w, a1.x, a1.y, a1.z, a1.w};
        float br[4] = {bv.x, bv.y, bv.z, bv.w};
        #pragma unroll
        for (int r = 0; r < 8; ++r)
            #pragma unroll
            for (int c = 0; c < 4; ++c)
                acc[r][c] = fmaf(w, fabsf(ar[r] + br[c]), acc[r][c]);
    }
    __syncthreads();                     // (3) P3 reads done; lin visible

    // ---- add linear terms ----
    {
        float cai[8], cbj[4];
        #pragma unroll
        for (int r = 0; r < 8; ++r) cai[r] = sa.lin[0][ty * 8 + r];
        #pragma unroll
        for (int c = 0; c < 4; ++c) cbj[c] = sa.lin[1][tx * 4 + c];
        #pragma unroll
        for (int r = 0; r < 8; ++r)
            #pragma unroll
            for (int c = 0; c < 4; ++c)
                acc[r][c] += cai[r] + cbj[c];
    }

    // ---- epilogue: S -> bf16 LDS (st overlays spa/spb, safe after (3)) ----
    #pragma unroll
    for (int r = 0; r < 8; ++r) {
        unsigned int p0 = ((unsigned int)f2bf(acc[r][1]) << 16) | f2bf(acc[r][0]);
        unsigned int p1 = ((unsigned int)f2bf(acc[r][3]) << 16) | f2bf(acc[r][2]);
        *(uint2*)&sb.st[ty * 8 + r][tx * 4] = make_uint2(p0, p1);
    }
    __syncthreads();                     // (4) S tile complete

    unsigned short* Dn = Dp + (size_t)n * (D * D);
    #pragma unroll
    for (int half = 0; half < 2; ++half) {
        const int iq4 = ty * 2 + half;   // i-quad 0..31
        float dre[4][4];
        #pragma unroll
        for (int c = 0; c < 4; ++c) {
            int j = tx * 4 + c;
            uint2 tv = *(const uint2*)&sb.st[j][iq4 * 4];  // S[j][iq4*4..+3]
            dre[0][c] = acc[half * 4 + 0][c] - bf2f(tv.x & 0xffff);
            dre[1][c] = acc[half * 4 + 1][c] - bf2f(tv.x >> 16);
            dre[2][c] = acc[half * 4 + 2][c] - bf2f(tv.y & 0xffff);
            dre[3][c] = acc[half * 4 + 3][c] - bf2f(tv.y >> 16);
        }
        #pragma unroll
        for (int r = 0; r < 4; ++r) {
            unsigned int p0 = ((unsigned int)f2bf(dre[r][1]) << 16) | f2bf(dre[r][0]);
            unsigned int p1 = ((unsigned int)f2bf(dre[r][3]) << 16) | f2bf(dre[r][2]);
            *(uint2*)&Dn[(iq4 * 4 + r) * D + tx * 4] = make_uint2(p0, p1);
        }
    }
}

// ---------------------------------------------------------------------------
// K3: mean over n of D (8 MB, coalesced uint2), sigmoid/Wm finalize.
// grid 256: block = (row, j-half). thread (g = 16 n-groups, jq = 16 j-quads).
// ---------------------------------------------------------------------------
__global__ __launch_bounds__(256) void finalize_kernel(
    const unsigned short* __restrict__ Dp, const float* __restrict__ Wmag,
    float* __restrict__ out)
{
    __shared__ float red[16][68];

    const int t    = threadIdx.x;
    const int row  = blockIdx.x >> 1;
    const int half = blockIdx.x & 1;
    const int g    = t >> 4;             // n-group 0..15 (16 n's each)
    const int jq   = t & 15;             // j-quad within half
    const int jloc = jq * 4;

    float a4[4] = {0.f, 0.f, 0.f, 0.f};
    #pragma unroll 4
    for (int q = 0; q < 16; ++q) {
        int nn = g * 16 + q;
        uint2 u = *(const uint2*)&Dp[(size_t)nn * (D * D) + row * D + half * 64 + jloc];
        a4[0] += bf2f(u.x & 0xffff); a4[1] += bf2f(u.x >> 16);
        a4[2] += bf2f(u.y & 0xffff); a4[3] += bf2f(u.y >> 16);
    }
    *(float4*)&red[g][jloc] = make_float4(a4[0], a4[1], a4[2], a4[3]);
    __syncthreads();

    if (t < 64) {
        const int j = half * 64 + t;
        float s = 0.f;
        #pragma unroll
        for (int gg = 0; gg < 16; ++gg) s += red[gg][t];

        const int idx = row * D + j;
        float av  = s * (1.0f / 256.0f);     // mean over n; TAU = 1
        float dir = 1.0f / (1.0f + __expf(-av));
        float wm  = 0.5f * (Wmag[row * D + j] + Wmag[j * D + row]);
        float A;
        if (row == j) { wm = 0.f; A = 0.f; }
        else          { A = dir / (1.0f + __expf(-wm)); }
        out[idx]         = A;
        out[D * D + idx] = wm;
    }
}

extern "C" void kernel_launch(void* const* d_in, const int* in_sizes, int n_in,
                              void* d_out, int out_size, void* d_ws, size_t ws_size,
                              hipStream_t stream)
{
    const float* z    = (const float*)d_in[0];   // (4,64,128,32)
    const float* Wmag = (const float*)d_in[1];   // (128,128)
    const float* W1   = (const float*)d_in[2];   // (32,64)
    const float* b1   = (const float*)d_in[3];   // (32,)
    const float* W2   = (const float*)d_in[4];   // (1,32)
    // d_in[5] = b2: cancels in scores - scores^T.

    unsigned short* Dp = (unsigned short*)d_ws;  // bf16 D[n][i][j], 8 MB
    float* out = (float*)d_out;

    fused_pab_scores<<<NT, 512, 0, stream>>>(z, W1, b1, W2, Dp);
    finalize_kernel<<<NT, 256, 0, stream>>>(Dp, Wmag, out);
}